// Round 1
// baseline (737.293 us; speedup 1.0000x reference)
//
#include <hip/hip_runtime.h>

// ---------------------------------------------------------------------------
// SerializedAttention on MI355X (gfx950), bf16 MFMA pipeline.
// N=65536, B=4, C=512, K=256 (patch), H=8, dh=64, n_chunks=256, tokens=257.
// Stages: cast/gather -> QKV GEMM (bf16 mfma) -> per-(chunk,head) attention
//         -> proj GEMM (fp32 out) ; cls path in fp32 (tiny).
// ---------------------------------------------------------------------------

typedef float  floatx4 __attribute__((ext_vector_type(4)));
typedef __bf16 bf16x8  __attribute__((ext_vector_type(8)));

__device__ __forceinline__ __bf16 f2bf(float x) {
  unsigned u = __builtin_bit_cast(unsigned, x);
  u = u + 0x7FFFu + ((u >> 16) & 1u);                // RNE
  unsigned short h = (unsigned short)(u >> 16);
  return __builtin_bit_cast(__bf16, h);
}

__device__ __forceinline__ floatx4 mfma_16x16x32(bf16x8 a, bf16x8 b, floatx4 c) {
  return __builtin_amdgcn_mfma_f32_16x16x32_bf16(a, b, c, 0, 0, 0);
}

// async global->LDS, 16B per lane; LDS dest = wave-uniform base + lane*16
__device__ __forceinline__ void gload16(const void* g, void* l) {
  __builtin_amdgcn_global_load_lds(
      (const __attribute__((address_space(1))) unsigned int*)g,
      (__attribute__((address_space(3))) unsigned int*)l, 16, 0, 0);
}

// ---------------------------------------------------------------------------
// cast + gather: dst[m][0:512] = bf16(feat[order[m]][0:512])   (serial order)
// ---------------------------------------------------------------------------
__global__ void cast_gather_feat(const float* __restrict__ feat,
                                 const int* __restrict__ order,
                                 __bf16* __restrict__ dst) {
  long i = ((long)blockIdx.x * blockDim.x + threadIdx.x) * 8;
  int row = (int)(i >> 9);
  int col = (int)(i & 511);
  const float* sp = feat + (long)order[row] * 512 + col;
  float4 a = *(const float4*)sp;
  float4 b = *(const float4*)(sp + 4);
  bf16x8 o;
  o[0] = f2bf(a.x); o[1] = f2bf(a.y); o[2] = f2bf(a.z); o[3] = f2bf(a.w);
  o[4] = f2bf(b.x); o[5] = f2bf(b.y); o[6] = f2bf(b.z); o[7] = f2bf(b.w);
  *(bf16x8*)(dst + i) = o;
}

// Wt[n][k] = bf16(W[k][n])   (W: [K][N] fp32 row-major)
__global__ void cast_wT(const float* __restrict__ W, __bf16* __restrict__ Wt,
                        int K, int N, int total) {
  int i = blockIdx.x * blockDim.x + threadIdx.x;
  if (i >= total) return;
  int n = i / K, k = i - n * K;
  Wt[i] = f2bf(W[(long)k * N + n]);
}

// cls_qkv[b][n] = bf16( cls_tokens[b] . Wqkv[:,n] + bqkv[n] )   (fp32 math)
__global__ void cls_qkv_kernel(const float* __restrict__ cls_tokens,
                               const float* __restrict__ Wqkv,
                               const float* __restrict__ bqkv,
                               __bf16* __restrict__ clsqkv, int Bn, int C, int N3) {
  int i = blockIdx.x * blockDim.x + threadIdx.x;
  if (i >= Bn * N3) return;
  int b = i / N3, n = i - b * N3;
  float sv = bqkv[n];
  for (int k = 0; k < C; ++k) sv += cls_tokens[b * C + k] * Wqkv[(long)k * N3 + n];
  clsqkv[i] = f2bf(sv);
}

// ---------------------------------------------------------------------------
// GEMM: C[m][n] = sum_k A[m][k] * Bt[n][k]  (+bias[n]); 128x128 tile, BK=64.
// LDS staged via global_load_lds w16; XOR swizzle (c8' = c8 ^ (row&7)) so the
// 16-lane ds_read_b128 fragment reads spread over all 8 16B bank groups.
// ---------------------------------------------------------------------------
template <int OUT_F32>
__global__ __launch_bounds__(256, 2) void gemm_bt(
    const __bf16* __restrict__ A, const __bf16* __restrict__ Bt,
    const float* __restrict__ bias, void* __restrict__ C,
    int N, int K) {
  __shared__ __align__(16) __bf16 As[128 * 64];
  __shared__ __align__(16) __bf16 Bs[128 * 64];
  const int tid = threadIdx.x;
  const int wave = tid >> 6, lane = tid & 63;
  const int quad = lane >> 4, l15 = lane & 15;
  const int wr = wave >> 1, wc = wave & 1;
  const long m0 = (long)blockIdx.x * 128;
  const int n0 = blockIdx.y * 128;
  const int srow8 = lane >> 3;   // row within 8-row group
  const int sc8p = lane & 7;     // stored 16B slot (c8')

  floatx4 zero = {0.f, 0.f, 0.f, 0.f};
  floatx4 acc[4][4];
#pragma unroll
  for (int i = 0; i < 4; ++i)
#pragma unroll
    for (int j = 0; j < 4; ++j) acc[i][j] = zero;

  for (int kt = 0; kt < K; kt += 64) {
    __syncthreads();
#pragma unroll
    for (int i = 0; i < 4; ++i) {
      const int rbase = i * 32 + wave * 8;
      const int row = rbase + srow8;
      const int c8 = sc8p ^ (row & 7);
      gload16(A + (m0 + row) * K + kt + c8 * 8, As + rbase * 64);
      gload16(Bt + (long)(n0 + row) * K + kt + c8 * 8, Bs + rbase * 64);
    }
    __syncthreads();
#pragma unroll
    for (int ks = 0; ks < 2; ++ks) {
      bf16x8 af[4], bfr[4];
#pragma unroll
      for (int mi = 0; mi < 4; ++mi) {
        int row = wr * 64 + mi * 16 + l15;
        int c8 = ks * 4 + quad;
        af[mi] = *(const bf16x8*)(As + row * 64 + ((c8 ^ (row & 7)) << 3));
      }
#pragma unroll
      for (int ni = 0; ni < 4; ++ni) {
        int row = wc * 64 + ni * 16 + l15;
        int c8 = ks * 4 + quad;
        bfr[ni] = *(const bf16x8*)(Bs + row * 64 + ((c8 ^ (row & 7)) << 3));
      }
#pragma unroll
      for (int mi = 0; mi < 4; ++mi)
#pragma unroll
        for (int ni = 0; ni < 4; ++ni)
          acc[mi][ni] = mfma_16x16x32(af[mi], bfr[ni], acc[mi][ni]);
    }
  }
  // epilogue: C layout col=lane&15, row=quad*4+reg
#pragma unroll
  for (int mi = 0; mi < 4; ++mi) {
#pragma unroll
    for (int ni = 0; ni < 4; ++ni) {
      const int col = n0 + wc * 64 + ni * 16 + l15;
      const float bb = bias[col];
#pragma unroll
      for (int r = 0; r < 4; ++r) {
        const long row = m0 + wr * 64 + mi * 16 + quad * 4 + r;
        float v = acc[mi][ni][r] + bb;
        if (OUT_F32)
          ((float*)C)[row * N + col] = v;
        else
          ((__bf16*)C)[row * N + col] = f2bf(v);
      }
    }
  }
}

// ---------------------------------------------------------------------------
// Attention: one block per (chunk, head). 257 tokens (0=cls), keys padded 288.
// S = Q K^T: Q/K frags straight from global (L1-resident). V transposed in LDS.
// Full-row softmax in registers, P via small per-wave LDS transpose buffer.
// Token outputs scattered to ORIGINAL order (fuses the `inverse` gather).
// ---------------------------------------------------------------------------
__global__ __launch_bounds__(256, 2) void attn_kernel(
    const __bf16* __restrict__ qkv,     // [65536][1536] serial order
    const __bf16* __restrict__ clsqkv,  // [4][1536]
    const int* __restrict__ order,      // [65536]
    const int* __restrict__ offset,     // [B]
    __bf16* __restrict__ outO,          // [65536][512] original order
    float* __restrict__ outcls,         // [256][512]
    int B) {
  __shared__ __align__(16) __bf16 Vt[64 * 296];     // V^T: [dh][key], stride 296
  __shared__ __align__(16) __bf16 Pbuf[4 * 16 * 40];// per-wave 16x(32+8)
  const int chunk = blockIdx.x >> 3;
  const int h = blockIdx.x & 7;
  const int tid = threadIdx.x;
  const int wave = tid >> 6, lane = tid & 63;
  const int quad = lane >> 4, l15 = lane & 15;
  const int cs = chunk << 8;
  int batch = 0;
  for (int b = 0; b < B; ++b) batch += (offset[b] <= cs) ? 1 : 0;
  const __bf16* clsrow = clsqkv + (long)batch * 1536;
  const int qoff = h * 64;
  const int koff = 512 + h * 64;
  const int voff = 1024 + h * 64;

  // ---- stage Vt (transpose): Vt[d*296 + t] = V[t][d] ----
  {
    int t = tid;  // tokens 0..255
    const __bf16* rp = (t == 0) ? clsrow : (qkv + (long)(cs + t - 1) * 1536);
#pragma unroll
    for (int i = 0; i < 8; ++i) {
      bf16x8 v = *(const bf16x8*)(rp + voff + i * 8);
#pragma unroll
      for (int j = 0; j < 8; ++j) Vt[(i * 8 + j) * 296 + t] = v[j];
    }
  }
  if (tid < 32) {
    int t = 256 + tid;
    if (t == 256) {
      const __bf16* rp = qkv + (long)(cs + 255) * 1536;
#pragma unroll
      for (int i = 0; i < 8; ++i) {
        bf16x8 v = *(const bf16x8*)(rp + voff + i * 8);
#pragma unroll
        for (int j = 0; j < 8; ++j) Vt[(i * 8 + j) * 296 + t] = v[j];
      }
    } else {
      const __bf16 z = f2bf(0.f);
      for (int d = 0; d < 64; ++d) Vt[d * 296 + t] = z;
    }
  }
  __syncthreads();

  __bf16* Pw = Pbuf + wave * 640;

  for (int rt = wave; rt < 17; rt += 4) {  // query row-tiles, no barriers inside
    // Q fragments (A operand: m=lane&15, k=quad*8+j)
    int qtok = rt * 16 + l15;
    const __bf16* qp = (qtok == 0) ? clsrow
                       : (qkv + (long)(cs + ((qtok <= 256) ? qtok : 256) - 1) * 1536);
    bf16x8 qf0 = *(const bf16x8*)(qp + qoff + quad * 8);
    bf16x8 qf1 = *(const bf16x8*)(qp + qoff + 32 + quad * 8);

    floatx4 zero = {0.f, 0.f, 0.f, 0.f};
    floatx4 s[18];
#pragma unroll
    for (int i = 0; i < 18; ++i) s[i] = zero;
#pragma unroll
    for (int kt2 = 0; kt2 < 18; ++kt2) {
      int ktok = kt2 * 16 + l15;
      const __bf16* kp = (ktok == 0) ? clsrow
                         : (qkv + (long)(cs + ((ktok <= 256) ? ktok : 256) - 1) * 1536);
      bf16x8 kf0 = *(const bf16x8*)(kp + koff + quad * 8);
      bf16x8 kf1 = *(const bf16x8*)(kp + koff + 32 + quad * 8);
      s[kt2] = mfma_16x16x32(qf0, kf0, s[kt2]);
      s[kt2] = mfma_16x16x32(qf1, kf1, s[kt2]);
    }
    // ---- softmax over 257 valid keys (cols >=257 masked) ----
    float mx[4] = {-3.0e38f, -3.0e38f, -3.0e38f, -3.0e38f};
#pragma unroll
    for (int kt2 = 0; kt2 < 18; ++kt2) {
      const bool valid = (kt2 * 16 + l15) < 257;
#pragma unroll
      for (int r = 0; r < 4; ++r) {
        float v = s[kt2][r] * 0.125f;  // dh^-0.5
        v = valid ? v : -3.0e38f;
        s[kt2][r] = v;
        mx[r] = fmaxf(mx[r], v);
      }
    }
#pragma unroll
    for (int off = 1; off < 16; off <<= 1)
#pragma unroll
      for (int r = 0; r < 4; ++r) mx[r] = fmaxf(mx[r], __shfl_xor(mx[r], off, 16));
    float sum[4] = {0.f, 0.f, 0.f, 0.f};
#pragma unroll
    for (int kt2 = 0; kt2 < 18; ++kt2)
#pragma unroll
      for (int r = 0; r < 4; ++r) {
        float e = __expf(s[kt2][r] - mx[r]);
        s[kt2][r] = e;
        sum[r] += e;
      }
#pragma unroll
    for (int off = 1; off < 16; off <<= 1)
#pragma unroll
      for (int r = 0; r < 4; ++r) sum[r] += __shfl_xor(sum[r], off, 16);
    float rl[4];
#pragma unroll
    for (int r = 0; r < 4; ++r) rl[r] = 1.0f / sum[r];

    // ---- PV: P through per-wave LDS transpose, V^T frags from LDS ----
    floatx4 o[4];
#pragma unroll
    for (int i = 0; i < 4; ++i) o[i] = zero;
#pragma unroll
    for (int ks = 0; ks < 9; ++ks) {
#pragma unroll
      for (int half = 0; half < 2; ++half) {
        int kt2 = ks * 2 + half;
#pragma unroll
        for (int r = 0; r < 4; ++r)
          Pw[(quad * 4 + r) * 40 + half * 16 + l15] = f2bf(s[kt2][r] * rl[r]);
      }
      asm volatile("s_waitcnt lgkmcnt(0)" ::: "memory");  // in-wave write->read
      bf16x8 pf = *(const bf16x8*)(Pw + l15 * 40 + quad * 8);
#pragma unroll
      for (int ni = 0; ni < 4; ++ni) {
        bf16x8 vf = *(const bf16x8*)(Vt + (ni * 16 + l15) * 296 + ks * 32 + quad * 8);
        o[ni] = mfma_16x16x32(pf, vf, o[ni]);
      }
    }
    // ---- store: rows q = rt*16 + quad*4 + r ; col = dh = ni*16 + l15 ----
#pragma unroll
    for (int r = 0; r < 4; ++r) {
      int q = rt * 16 + quad * 4 + r;
      if (q > 256) continue;
      if (q == 0) {
#pragma unroll
        for (int ni = 0; ni < 4; ++ni)
          outcls[(long)chunk * 512 + h * 64 + ni * 16 + l15] = o[ni][r];
      } else {
        long orow = (long)order[cs + q - 1];  // scatter back to original order
#pragma unroll
        for (int ni = 0; ni < 4; ++ni)
          outO[orow * 512 + h * 64 + ni * 16 + l15] = f2bf(o[ni][r]);
      }
    }
  }
}

// cls_feat[b][c] = mean over batch-b chunks of outcls[chunk][c]
__global__ void cls_feat_kernel(const float* __restrict__ outcls,
                                const int* __restrict__ offset,
                                float* __restrict__ dst, int B, int C) {
  int i = blockIdx.x * blockDim.x + threadIdx.x;
  if (i >= B * C) return;
  int b = i / C, c = i - b * C;
  int st = (b == 0) ? 0 : offset[b - 1];
  int en = offset[b];
  int c0 = st >> 8, c1 = en >> 8;
  float s = 0.f;
  for (int ch = c0; ch < c1; ++ch) s += outcls[(long)ch * C + c];
  dst[i] = s / (float)(c1 - c0);
}

// ---------------------------------------------------------------------------
extern "C" void kernel_launch(void* const* d_in, const int* in_sizes, int n_in,
                              void* d_out, int out_size, void* d_ws, size_t ws_size,
                              hipStream_t stream) {
  const float* feat       = (const float*)d_in[0];
  const float* cls_tokens = (const float*)d_in[1];
  const float* Wqkv       = (const float*)d_in[2];
  const float* bqkv       = (const float*)d_in[3];
  const float* Wproj      = (const float*)d_in[4];
  const float* bproj      = (const float*)d_in[5];
  const int*   order      = (const int*)d_in[6];
  // const int* inverse    = (const int*)d_in[7];   // fused via scatter-on-write
  const int*   offset     = (const int*)d_in[8];
  const int B = in_sizes[8];  // 4

  // workspace layout (bytes): total ~271 MB
  char* ws = (char*)d_ws;
  __bf16* qkv    = (__bf16*)(ws);                   // 65536*1536*2 = 201326592
  __bf16* featb  = (__bf16*)(ws + 201326592);       // 65536*512*2  =  67108864
  __bf16* outO   = featb;                           // reuse: featb dead after gemm1
  __bf16* wqkvT  = (__bf16*)(ws + 268435456);       // 1536*512*2   =   1572864
  __bf16* wprojT = (__bf16*)(ws + 270008320);       // 512*512*2    =    524288
  __bf16* clsqkv = (__bf16*)(ws + 270532608);       // 4*1536*2     =     12288
  float*  outcls = (float*)(ws + 270544896);        // 256*512*4    =    524288

  float* feat_out = (float*)d_out;                  // [65536][512]
  float* cls_out  = feat_out + (long)65536 * 512;   // [4][512]

  // 1) casts / transposes / cls qkv
  cast_gather_feat<<<16384, 256, 0, stream>>>(feat, order, featb);
  cast_wT<<<3072, 256, 0, stream>>>(Wqkv, wqkvT, 512, 1536, 512 * 1536);
  cast_wT<<<1024, 256, 0, stream>>>(Wproj, wprojT, 512, 512, 512 * 512);
  cls_qkv_kernel<<<24, 256, 0, stream>>>(cls_tokens, Wqkv, bqkv, clsqkv, B, 512, 1536);

  // 2) QKV GEMM: qkv[serial m][1536] = featb @ Wqkv + bqkv   (bf16 out)
  gemm_bt<0><<<dim3(512, 12), 256, 0, stream>>>(featb, wqkvT, bqkv, (void*)qkv, 1536, 512);

  // 3) attention per (chunk, head); writes outO (orig order) + outcls
  attn_kernel<<<2048, 256, 0, stream>>>(qkv, clsqkv, order, offset, outO, outcls, B);

  // 4) proj GEMM: feat_out = outO @ Wproj + bproj   (fp32 out)
  gemm_bt<1><<<dim3(512, 4), 256, 0, stream>>>(outO, wprojT, bproj, (void*)feat_out, 512, 512);

  // 5) cls mean
  cls_feat_kernel<<<8, 256, 0, stream>>>(outcls, offset, cls_out, B, 512);
}

// Round 3
// 688.810 us; speedup vs baseline: 1.0704x; 1.0704x over previous
//
#include <hip/hip_runtime.h>

// ---------------------------------------------------------------------------
// SerializedAttention on MI355X (gfx950), bf16 MFMA pipeline.
// N=65536, B=4, C=512, K=256 (patch), H=8, dh=64, n_chunks=256, tokens=257.
// ---------------------------------------------------------------------------

typedef float  floatx4 __attribute__((ext_vector_type(4)));
typedef __bf16 bf16x8  __attribute__((ext_vector_type(8)));

__device__ __forceinline__ __bf16 f2bf(float x) {
  unsigned u = __builtin_bit_cast(unsigned, x);
  u = u + 0x7FFFu + ((u >> 16) & 1u);                // RNE
  unsigned short h = (unsigned short)(u >> 16);
  return __builtin_bit_cast(__bf16, h);
}

__device__ __forceinline__ floatx4 mfma_16x16x32(bf16x8 a, bf16x8 b, floatx4 c) {
  return __builtin_amdgcn_mfma_f32_16x16x32_bf16(a, b, c, 0, 0, 0);
}

// async global->LDS, 16B per lane; LDS dest = wave-uniform base + lane*16
__device__ __forceinline__ void gload16(const void* g, void* l) {
  __builtin_amdgcn_global_load_lds(
      (const __attribute__((address_space(1))) unsigned int*)g,
      (__attribute__((address_space(3))) unsigned int*)l, 16, 0, 0);
}

// ---------------------------------------------------------------------------
// cast + gather: dst[m][0:512] = bf16(feat[order[m]][0:512])   (serial order)
// ---------------------------------------------------------------------------
__global__ void cast_gather_feat(const float* __restrict__ feat,
                                 const int* __restrict__ order,
                                 __bf16* __restrict__ dst) {
  long i = ((long)blockIdx.x * blockDim.x + threadIdx.x) * 8;
  int row = (int)(i >> 9);
  int col = (int)(i & 511);
  const float* sp = feat + (long)order[row] * 512 + col;
  float4 a = *(const float4*)sp;
  float4 b = *(const float4*)(sp + 4);
  bf16x8 o;
  o[0] = f2bf(a.x); o[1] = f2bf(a.y); o[2] = f2bf(a.z); o[3] = f2bf(a.w);
  o[4] = f2bf(b.x); o[5] = f2bf(b.y); o[6] = f2bf(b.z); o[7] = f2bf(b.w);
  *(bf16x8*)(dst + i) = o;
}

// Wt[n][k] = bf16(W[k][n]) via 32x32 LDS tile (coalesced both sides).
// grid: (N/32, K/32), block 256.
__global__ void transpose_cast(const float* __restrict__ W, __bf16* __restrict__ Wt,
                               int K, int N) {
  __shared__ float tile[32][33];
  const int n0 = blockIdx.x * 32, k0 = blockIdx.y * 32;
  const int c = threadIdx.x & 31, r8 = threadIdx.x >> 5;
#pragma unroll
  for (int i = 0; i < 4; ++i) {
    int r = r8 + i * 8;
    tile[r][c] = W[(long)(k0 + r) * N + n0 + c];
  }
  __syncthreads();
#pragma unroll
  for (int i = 0; i < 4; ++i) {
    int r = r8 + i * 8;  // n-index within tile
    Wt[(long)(n0 + r) * K + k0 + c] = f2bf(tile[c][r]);
  }
}

// cls_qkv[b][n] = bf16( cls_tokens[b] . Wqkv[:,n] + bqkv[n] ); k-split x4.
// grid 96, block 256: 64 outputs x 4 k-parts per block.
__global__ void cls_qkv_kernel(const float* __restrict__ cls_tokens,
                               const float* __restrict__ Wqkv,
                               const float* __restrict__ bqkv,
                               __bf16* __restrict__ clsqkv, int N3) {
  __shared__ float red[256];
  const int c = threadIdx.x & 63, part = threadIdx.x >> 6;
  const int o = blockIdx.x * 64 + c;
  const int b = o / N3, n = o - b * N3;
  float sv = 0.f;
  const int kst = part * 128;
  for (int k = kst; k < kst + 128; ++k)
    sv += cls_tokens[b * 512 + k] * Wqkv[(long)k * N3 + n];
  red[threadIdx.x] = sv;
  __syncthreads();
  if (part == 0)
    clsqkv[o] = f2bf(red[c] + red[c + 64] + red[c + 128] + red[c + 192] + bqkv[n]);
}

// ---------------------------------------------------------------------------
// GEMM: C[m][n] = sum_k A[m][k] * Bt[n][k]  (+bias[n]); 128x128 tile, BK=64.
// ---------------------------------------------------------------------------
template <int OUT_F32>
__global__ __launch_bounds__(256, 2) void gemm_bt(
    const __bf16* __restrict__ A, const __bf16* __restrict__ Bt,
    const float* __restrict__ bias, void* __restrict__ C,
    int N, int K) {
  __shared__ __align__(16) __bf16 As[128 * 64];
  __shared__ __align__(16) __bf16 Bs[128 * 64];
  const int tid = threadIdx.x;
  const int wave = tid >> 6, lane = tid & 63;
  const int quad = lane >> 4, l15 = lane & 15;
  const int wr = wave >> 1, wc = wave & 1;
  const long m0 = (long)blockIdx.x * 128;
  const int n0 = blockIdx.y * 128;
  const int srow8 = lane >> 3;
  const int sc8p = lane & 7;

  floatx4 zero = {0.f, 0.f, 0.f, 0.f};
  floatx4 acc[4][4];
#pragma unroll
  for (int i = 0; i < 4; ++i)
#pragma unroll
    for (int j = 0; j < 4; ++j) acc[i][j] = zero;

  for (int kt = 0; kt < K; kt += 64) {
    __syncthreads();
#pragma unroll
    for (int i = 0; i < 4; ++i) {
      const int rbase = i * 32 + wave * 8;
      const int row = rbase + srow8;
      const int c8 = sc8p ^ (row & 7);
      gload16(A + (m0 + row) * K + kt + c8 * 8, As + rbase * 64);
      gload16(Bt + (long)(n0 + row) * K + kt + c8 * 8, Bs + rbase * 64);
    }
    __syncthreads();
#pragma unroll
    for (int ks = 0; ks < 2; ++ks) {
      bf16x8 af[4], bfr[4];
#pragma unroll
      for (int mi = 0; mi < 4; ++mi) {
        int row = wr * 64 + mi * 16 + l15;
        int c8 = ks * 4 + quad;
        af[mi] = *(const bf16x8*)(As + row * 64 + ((c8 ^ (row & 7)) << 3));
      }
#pragma unroll
      for (int ni = 0; ni < 4; ++ni) {
        int row = wc * 64 + ni * 16 + l15;
        int c8 = ks * 4 + quad;
        bfr[ni] = *(const bf16x8*)(Bs + row * 64 + ((c8 ^ (row & 7)) << 3));
      }
#pragma unroll
      for (int mi = 0; mi < 4; ++mi)
#pragma unroll
        for (int ni = 0; ni < 4; ++ni)
          acc[mi][ni] = mfma_16x16x32(af[mi], bfr[ni], acc[mi][ni]);
    }
  }
#pragma unroll
  for (int mi = 0; mi < 4; ++mi) {
#pragma unroll
    for (int ni = 0; ni < 4; ++ni) {
      const int col = n0 + wc * 64 + ni * 16 + l15;
      const float bb = bias[col];
#pragma unroll
      for (int r = 0; r < 4; ++r) {
        const long row = m0 + wr * 64 + mi * 16 + quad * 4 + r;
        float v = acc[mi][ni][r] + bb;
        if (OUT_F32)
          ((float*)C)[row * N + col] = v;
        else
          ((__bf16*)C)[row * N + col] = f2bf(v);
      }
    }
  }
}

// ---------------------------------------------------------------------------
// Attention: one block per (chunk, head), chunk = blockIdx&255 (XCD-grouped).
// 257 tokens (0=cls). 17 S key-tiles (272 cols, only col<=256 valid).
// PV: keys 0..255 via MFMA (Vt in LDS), key 256 via shfl-broadcast rank-1.
// LDS: Vt 64x264 (stride 528B=16*33: 16B-aligned, conflict-free row reads)
//      + Pbuf 4x16x40 (stride 80B=16*5) + ktab[272] = 40000 B -> 4 blocks/CU.
// ---------------------------------------------------------------------------
__global__ __launch_bounds__(256, 4) void attn_kernel(
    const __bf16* __restrict__ qkv,     // [65536][1536] serial order
    const __bf16* __restrict__ clsqkv,  // [4][1536]
    const int* __restrict__ order,      // [65536]
    const int* __restrict__ offset,     // [B]
    __bf16* __restrict__ outO,          // [65536][512] original order
    float* __restrict__ outcls,         // [256][512]
    int B) {
  __shared__ __align__(16) __bf16 Vt[64 * 264];
  __shared__ __align__(16) __bf16 Pbuf[4 * 16 * 40];
  __shared__ unsigned ktab[272];
  const int chunk = blockIdx.x & 255;
  const int h = blockIdx.x >> 8;
  const int tid = threadIdx.x;
  const int wave = tid >> 6, lane = tid & 63;
  const int quad = lane >> 4, l15 = lane & 15;
  const int cs = chunk << 8;
  int batch = 0;
  for (int b = 0; b < B; ++b) batch += (offset[b] <= cs) ? 1 : 0;
  const unsigned clsoff =
      (unsigned)((const char*)(clsqkv + (long)batch * 1536) - (const char*)qkv);

  for (int t = tid; t < 272; t += 256)   // ALL 272 entries (fix: was tid<272)
    ktab[t] = (t == 0) ? clsoff : (unsigned)(cs + ((t <= 256) ? t : 256) - 1) * 3072u;

  const int qoffB = h * 128;
  const int koffB = 1024 + h * 128;
  const int voffB = 2048 + h * 128;

  // ---- stage Vt coalesced: 8 lanes per row, 16B each ----
  {
    const int rsub = lane >> 3, c8 = lane & 7;
#pragma unroll
    for (int p = 0; p < 8; ++p) {
      int t = p * 32 + wave * 8 + rsub;  // token 0..255
      unsigned ro = (t == 0) ? clsoff : (unsigned)(cs + t - 1) * 3072u;
      bf16x8 v = *(const bf16x8*)((const char*)qkv + ro + voffB + c8 * 16);
#pragma unroll
      for (int j = 0; j < 8; ++j) Vt[(c8 * 8 + j) * 264 + t] = v[j];
    }
    if (tid < 8) {  // token 256
      bf16x8 v = *(const bf16x8*)((const char*)qkv +
                                  (unsigned)(cs + 255) * 3072u + voffB + tid * 16);
#pragma unroll
      for (int j = 0; j < 8; ++j) Vt[(tid * 8 + j) * 264 + 256] = v[j];
    }
  }
  __syncthreads();

  float v256[4];
#pragma unroll
  for (int ni = 0; ni < 4; ++ni) v256[ni] = (float)Vt[(ni * 16 + l15) * 264 + 256];
  __bf16* Pw = Pbuf + wave * (16 * 40);

  for (int rt = wave; rt < 17; rt += 4) {
    const unsigned qo = ktab[rt * 16 + l15];
    bf16x8 qf0 = *(const bf16x8*)((const char*)qkv + qo + qoffB + quad * 16);
    bf16x8 qf1 = *(const bf16x8*)((const char*)qkv + qo + qoffB + 64 + quad * 16);

    floatx4 zero = {0.f, 0.f, 0.f, 0.f};
    floatx4 s[17];
#pragma unroll
    for (int i = 0; i < 17; ++i) s[i] = zero;
#pragma unroll
    for (int k2 = 0; k2 < 17; ++k2) {
      const unsigned ko = ktab[k2 * 16 + l15];
      bf16x8 kf0 = *(const bf16x8*)((const char*)qkv + ko + koffB + quad * 16);
      bf16x8 kf1 = *(const bf16x8*)((const char*)qkv + ko + koffB + 64 + quad * 16);
      s[k2] = mfma_16x16x32(qf0, kf0, s[k2]);
      s[k2] = mfma_16x16x32(qf1, kf1, s[k2]);
    }

    // ---- softmax (scale folded into exp2; mask only tile 16) ----
    float mx[4] = {-3.0e38f, -3.0e38f, -3.0e38f, -3.0e38f};
#pragma unroll
    for (int k2 = 0; k2 < 16; ++k2)
#pragma unroll
      for (int r = 0; r < 4; ++r) mx[r] = fmaxf(mx[r], s[k2][r]);
#pragma unroll
    for (int r = 0; r < 4; ++r) {
      float v = (l15 == 0) ? s[16][r] : -3.0e38f;
      s[16][r] = v;
      mx[r] = fmaxf(mx[r], v);
    }
#pragma unroll
    for (int off = 1; off < 16; off <<= 1)
#pragma unroll
      for (int r = 0; r < 4; ++r) mx[r] = fmaxf(mx[r], __shfl_xor(mx[r], off, 16));
    const float c1 = 0.125f * 1.44269504f;  // scale * log2(e)
    float mb[4], sum[4] = {0.f, 0.f, 0.f, 0.f};
#pragma unroll
    for (int r = 0; r < 4; ++r) mb[r] = mx[r] * c1;
#pragma unroll
    for (int k2 = 0; k2 < 17; ++k2)
#pragma unroll
      for (int r = 0; r < 4; ++r) {
        float e = __builtin_amdgcn_exp2f(fmaf(s[k2][r], c1, -mb[r]));
        s[k2][r] = e;
        sum[r] += e;
      }
#pragma unroll
    for (int off = 1; off < 16; off <<= 1)
#pragma unroll
      for (int r = 0; r < 4; ++r) sum[r] += __shfl_xor(sum[r], off, 16);
    float rl[4];
#pragma unroll
    for (int r = 0; r < 4; ++r) rl[r] = 1.0f / sum[r];

    // ---- PV: keys 0..255 via MFMA (unnormalized P), key 256 scalar ----
    floatx4 o[4];
#pragma unroll
    for (int i = 0; i < 4; ++i) o[i] = zero;
#pragma unroll
    for (int ks = 0; ks < 8; ++ks) {
#pragma unroll
      for (int half = 0; half < 2; ++half) {
        int kt2 = ks * 2 + half;
#pragma unroll
        for (int r = 0; r < 4; ++r)
          Pw[(quad * 4 + r) * 40 + half * 16 + l15] = f2bf(s[kt2][r]);
      }
      asm volatile("s_waitcnt lgkmcnt(0)" ::: "memory");
      bf16x8 pf = *(const bf16x8*)(Pw + l15 * 40 + quad * 8);
#pragma unroll
      for (int ni = 0; ni < 4; ++ni) {
        bf16x8 vf = *(const bf16x8*)(Vt + (ni * 16 + l15) * 264 + ks * 32 + quad * 8);
        o[ni] = mfma_16x16x32(pf, vf, o[ni]);
      }
    }
    float p256[4];
#pragma unroll
    for (int r = 0; r < 4; ++r) p256[r] = __shfl(s[16][r], lane & 48, 64);
#pragma unroll
    for (int ni = 0; ni < 4; ++ni)
#pragma unroll
      for (int r = 0; r < 4; ++r)
        o[ni][r] = (o[ni][r] + p256[r] * v256[ni]) * rl[r];

    // ---- store ----
#pragma unroll
    for (int r = 0; r < 4; ++r) {
      int q = rt * 16 + quad * 4 + r;
      if (q > 256) continue;
      if (q == 0) {
#pragma unroll
        for (int ni = 0; ni < 4; ++ni)
          outcls[(long)chunk * 512 + h * 64 + ni * 16 + l15] = o[ni][r];
      } else {
        long orow = (long)order[cs + q - 1];
#pragma unroll
        for (int ni = 0; ni < 4; ++ni)
          outO[orow * 512 + h * 64 + ni * 16 + l15] = f2bf(o[ni][r]);
      }
    }
  }
}

// cls_feat[b][c] = mean over batch-b chunks of outcls[chunk][c]
__global__ void cls_feat_kernel(const float* __restrict__ outcls,
                                const int* __restrict__ offset,
                                float* __restrict__ dst, int B, int C) {
  int i = blockIdx.x * blockDim.x + threadIdx.x;
  if (i >= B * C) return;
  int b = i / C, c = i - b * C;
  int st = (b == 0) ? 0 : offset[b - 1];
  int en = offset[b];
  int c0 = st >> 8, c1 = en >> 8;
  float s = 0.f;
  for (int ch = c0; ch < c1; ++ch) s += outcls[(long)ch * C + c];
  dst[i] = s / (float)(c1 - c0);
}

// ---------------------------------------------------------------------------
extern "C" void kernel_launch(void* const* d_in, const int* in_sizes, int n_in,
                              void* d_out, int out_size, void* d_ws, size_t ws_size,
                              hipStream_t stream) {
  const float* feat       = (const float*)d_in[0];
  const float* cls_tokens = (const float*)d_in[1];
  const float* Wqkv       = (const float*)d_in[2];
  const float* bqkv       = (const float*)d_in[3];
  const float* Wproj      = (const float*)d_in[4];
  const float* bproj      = (const float*)d_in[5];
  const int*   order      = (const int*)d_in[6];
  const int*   offset     = (const int*)d_in[8];
  const int B = in_sizes[8];  // 4

  char* ws = (char*)d_ws;
  __bf16* qkv    = (__bf16*)(ws);                   // 65536*1536*2 = 201326592
  __bf16* featb  = (__bf16*)(ws + 201326592);       // 65536*512*2  =  67108864
  __bf16* outO   = featb;                           // reuse after gemm1
  __bf16* wqkvT  = (__bf16*)(ws + 268435456);       // 1536*512*2
  __bf16* wprojT = (__bf16*)(ws + 270008320);       // 512*512*2
  __bf16* clsqkv = (__bf16*)(ws + 270532608);       // 4*1536*2
  float*  outcls = (float*)(ws + 270544896);        // 256*512*4

  float* feat_out = (float*)d_out;
  float* cls_out  = feat_out + (long)65536 * 512;

  cast_gather_feat<<<16384, 256, 0, stream>>>(feat, order, featb);
  transpose_cast<<<dim3(48, 16), 256, 0, stream>>>(Wqkv, wqkvT, 512, 1536);
  transpose_cast<<<dim3(16, 16), 256, 0, stream>>>(Wproj, wprojT, 512, 512);
  cls_qkv_kernel<<<96, 256, 0, stream>>>(cls_tokens, Wqkv, bqkv, clsqkv, 1536);

  gemm_bt<0><<<dim3(512, 12), 256, 0, stream>>>(featb, wqkvT, bqkv, (void*)qkv, 1536, 512);

  attn_kernel<<<2048, 256, 0, stream>>>(qkv, clsqkv, order, offset, outO, outcls, B);

  gemm_bt<1><<<dim3(512, 4), 256, 0, stream>>>(outO, wprojT, bproj, (void*)feat_out, 512, 512);

  cls_feat_kernel<<<8, 256, 0, stream>>>(outcls, offset, cls_out, B, 512);
}

// Round 4
// 609.011 us; speedup vs baseline: 1.2106x; 1.1310x over previous
//
#include <hip/hip_runtime.h>

// ---------------------------------------------------------------------------
// SerializedAttention on MI355X (gfx950), bf16 MFMA pipeline.
// N=65536, B=4, C=512, K=256 (patch), H=8, dh=64, n_chunks=256, tokens=257.
// ---------------------------------------------------------------------------

typedef float  floatx4 __attribute__((ext_vector_type(4)));
typedef __bf16 bf16x8  __attribute__((ext_vector_type(8)));

__device__ __forceinline__ __bf16 f2bf(float x) {
  unsigned u = __builtin_bit_cast(unsigned, x);
  u = u + 0x7FFFu + ((u >> 16) & 1u);                // RNE
  unsigned short h = (unsigned short)(u >> 16);
  return __builtin_bit_cast(__bf16, h);
}

__device__ __forceinline__ floatx4 mfma_16x16x32(bf16x8 a, bf16x8 b, floatx4 c) {
  return __builtin_amdgcn_mfma_f32_16x16x32_bf16(a, b, c, 0, 0, 0);
}

// async global->LDS, 16B per lane; global addr per-lane, LDS dest = uniform base + lane*16
__device__ __forceinline__ void gload16(const void* g, void* l) {
  __builtin_amdgcn_global_load_lds(
      (const __attribute__((address_space(1))) unsigned int*)g,
      (__attribute__((address_space(3))) unsigned int*)l, 16, 0, 0);
}

// ---------------------------------------------------------------------------
// cast + gather: dst[m][0:512] = bf16(feat[order[m]][0:512])   (serial order)
// ---------------------------------------------------------------------------
__global__ void cast_gather_feat(const float* __restrict__ feat,
                                 const int* __restrict__ order,
                                 __bf16* __restrict__ dst) {
  long i = ((long)blockIdx.x * blockDim.x + threadIdx.x) * 8;
  int row = (int)(i >> 9);
  int col = (int)(i & 511);
  const float* sp = feat + (long)order[row] * 512 + col;
  float4 a = *(const float4*)sp;
  float4 b = *(const float4*)(sp + 4);
  bf16x8 o;
  o[0] = f2bf(a.x); o[1] = f2bf(a.y); o[2] = f2bf(a.z); o[3] = f2bf(a.w);
  o[4] = f2bf(b.x); o[5] = f2bf(b.y); o[6] = f2bf(b.z); o[7] = f2bf(b.w);
  *(bf16x8*)(dst + i) = o;
}

// Wt[n][k] = bf16(W[k][n]) via 32x32 LDS tile (coalesced both sides).
__global__ void transpose_cast(const float* __restrict__ W, __bf16* __restrict__ Wt,
                               int K, int N) {
  __shared__ float tile[32][33];
  const int n0 = blockIdx.x * 32, k0 = blockIdx.y * 32;
  const int c = threadIdx.x & 31, r8 = threadIdx.x >> 5;
#pragma unroll
  for (int i = 0; i < 4; ++i) {
    int r = r8 + i * 8;
    tile[r][c] = W[(long)(k0 + r) * N + n0 + c];
  }
  __syncthreads();
#pragma unroll
  for (int i = 0; i < 4; ++i) {
    int r = r8 + i * 8;
    Wt[(long)(n0 + r) * K + k0 + c] = f2bf(tile[c][r]);
  }
}

// cls_qkv[b][n] = bf16( cls_tokens[b] . Wqkv[:,n] + bqkv[n] ); k-split x4.
__global__ void cls_qkv_kernel(const float* __restrict__ cls_tokens,
                               const float* __restrict__ Wqkv,
                               const float* __restrict__ bqkv,
                               __bf16* __restrict__ clsqkv, int N3) {
  __shared__ float red[256];
  const int c = threadIdx.x & 63, part = threadIdx.x >> 6;
  const int o = blockIdx.x * 64 + c;
  const int b = o / N3, n = o - b * N3;
  float sv = 0.f;
  const int kst = part * 128;
  for (int k = kst; k < kst + 128; ++k)
    sv += cls_tokens[b * 512 + k] * Wqkv[(long)k * N3 + n];
  red[threadIdx.x] = sv;
  __syncthreads();
  if (part == 0)
    clsqkv[o] = f2bf(red[c] + red[c + 64] + red[c + 128] + red[c + 192] + bqkv[n]);
}

// ---------------------------------------------------------------------------
// GEMM: C[m][n] = sum_k A[m][k] * Bt[n][k]  (+bias[n]); 128x128 tile, BK=64.
// blockIdx.x = COLUMN block (fast-varying) so consecutive blocks share the
// same A row-tile -> A stays L3/L2-hot instead of 12x HBM re-fetch.
// ---------------------------------------------------------------------------
template <int OUT_F32>
__global__ __launch_bounds__(256, 2) void gemm_bt(
    const __bf16* __restrict__ A, const __bf16* __restrict__ Bt,
    const float* __restrict__ bias, void* __restrict__ C,
    int N, int K) {
  __shared__ __align__(16) __bf16 As[128 * 64];
  __shared__ __align__(16) __bf16 Bs[128 * 64];
  const int tid = threadIdx.x;
  const int wave = tid >> 6, lane = tid & 63;
  const int quad = lane >> 4, l15 = lane & 15;
  const int wr = wave >> 1, wc = wave & 1;
  const long m0 = (long)blockIdx.y * 128;   // row block (slow)
  const int n0 = blockIdx.x * 128;          // col block (fast)
  const int srow8 = lane >> 3;
  const int sc8p = lane & 7;

  floatx4 zero = {0.f, 0.f, 0.f, 0.f};
  floatx4 acc[4][4];
#pragma unroll
  for (int i = 0; i < 4; ++i)
#pragma unroll
    for (int j = 0; j < 4; ++j) acc[i][j] = zero;

  for (int kt = 0; kt < K; kt += 64) {
    __syncthreads();
#pragma unroll
    for (int i = 0; i < 4; ++i) {
      const int rbase = i * 32 + wave * 8;
      const int row = rbase + srow8;
      const int c8 = sc8p ^ (row & 7);
      gload16(A + (m0 + row) * K + kt + c8 * 8, As + rbase * 64);
      gload16(Bt + (long)(n0 + row) * K + kt + c8 * 8, Bs + rbase * 64);
    }
    __syncthreads();
#pragma unroll
    for (int ks = 0; ks < 2; ++ks) {
      bf16x8 af[4], bfr[4];
#pragma unroll
      for (int mi = 0; mi < 4; ++mi) {
        int row = wr * 64 + mi * 16 + l15;
        int c8 = ks * 4 + quad;
        af[mi] = *(const bf16x8*)(As + row * 64 + ((c8 ^ (row & 7)) << 3));
      }
#pragma unroll
      for (int ni = 0; ni < 4; ++ni) {
        int row = wc * 64 + ni * 16 + l15;
        int c8 = ks * 4 + quad;
        bfr[ni] = *(const bf16x8*)(Bs + row * 64 + ((c8 ^ (row & 7)) << 3));
      }
#pragma unroll
      for (int mi = 0; mi < 4; ++mi)
#pragma unroll
        for (int ni = 0; ni < 4; ++ni)
          acc[mi][ni] = mfma_16x16x32(af[mi], bfr[ni], acc[mi][ni]);
    }
  }
#pragma unroll
  for (int mi = 0; mi < 4; ++mi) {
#pragma unroll
    for (int ni = 0; ni < 4; ++ni) {
      const int col = n0 + wc * 64 + ni * 16 + l15;
      const float bb = bias[col];
#pragma unroll
      for (int r = 0; r < 4; ++r) {
        const long row = m0 + wr * 64 + mi * 16 + quad * 4 + r;
        float v = acc[mi][ni][r] + bb;
        if (OUT_F32)
          ((float*)C)[row * N + col] = v;
        else
          ((__bf16*)C)[row * N + col] = f2bf(v);
      }
    }
  }
}

// ---------------------------------------------------------------------------
// Attention: one block per (chunk, head). 257 tokens (0=cls), 17 key tiles.
// K staged ONCE into LDS via global_load_lds (XOR chunk swizzle, stride 128B)
// -> S-phase reads are ds_read_b128, no redundant global gathers.
// Vt rows skewed by 8*((d>>3)&7) chunks -> staging writes bank-conflict-free.
// LDS: Ks 34816 + Vt 33920 + Pbuf 5120 = 73856 B -> 2 blocks/CU.
// ---------------------------------------------------------------------------
__global__ __launch_bounds__(256, 2) void attn_kernel(
    const __bf16* __restrict__ qkv,     // [65536][1536] serial order
    const __bf16* __restrict__ clsqkv,  // [4][1536]
    const int* __restrict__ order,      // [65536]
    const int* __restrict__ offset,     // [B]
    __bf16* __restrict__ outO,          // [65536][512] original order
    float* __restrict__ outcls,         // [256][512]
    int B) {
  __shared__ __align__(16) __bf16 Ks[272 * 64];        // K rows, stride 64 halves
  __shared__ __align__(16) __bf16 Vt[64 * 264 + 64];   // V^T, skewed rows
  __shared__ __align__(16) __bf16 Pbuf[4 * 16 * 40];
  const int chunk = blockIdx.x & 255;
  const int h = blockIdx.x >> 8;
  const int tid = threadIdx.x;
  const int wave = tid >> 6, lane = tid & 63;
  const int quad = lane >> 4, l15 = lane & 15;
  const int cs = chunk << 8;
  int batch = 0;
  for (int b = 0; b < B; ++b) batch += (offset[b] <= cs) ? 1 : 0;
  const unsigned clsoff =
      (unsigned)((const char*)(clsqkv + (long)batch * 1536) - (const char*)qkv);

  const int qoffB = h * 128;
  const int koffB = 1024 + h * 128;
  const int voffB = 2048 + h * 128;

  // token-row t (0=cls, 1..256 = chunk rows, >=257 dup last) -> byte offset
  auto rowoff = [&](int t) -> unsigned {
    int tt = (t <= 256) ? t : 256;
    return (tt == 0) ? clsoff : (unsigned)(cs + tt - 1) * 3072u;
  };

  // ---- stage Ks: 8 rows (1024B) per wave-issue; slot c8 holds chunk c8^(r&7)
  {
    const int rsub = lane >> 3, c8 = lane & 7;
    for (int i = wave; i < 34; i += 4) {
      int r = i * 8 + rsub;
      gload16((const char*)qkv + rowoff(r) + koffB + ((c8 ^ (r & 7)) << 4),
              Ks + i * 512);
    }
  }

  // ---- stage Vt (transpose, skewed rows): Vt[skew(d) + t] = V[t][d] ----
  {
    const int rsub = lane >> 3, c8 = lane & 7;
#pragma unroll
    for (int p = 0; p < 8; ++p) {
      int t = p * 32 + wave * 8 + rsub;  // token 0..255
      unsigned ro = (t == 0) ? clsoff : (unsigned)(cs + t - 1) * 3072u;
      bf16x8 v = *(const bf16x8*)((const char*)qkv + ro + voffB + c8 * 16);
#pragma unroll
      for (int j = 0; j < 8; ++j)
        Vt[(c8 * 8 + j) * 264 + c8 * 8 + t] = v[j];   // skew = 8*((d>>3)&7)
    }
    if (tid < 8) {  // token 256
      bf16x8 v = *(const bf16x8*)((const char*)qkv +
                                  (unsigned)(cs + 255) * 3072u + voffB + tid * 16);
#pragma unroll
      for (int j = 0; j < 8; ++j)
        Vt[(tid * 8 + j) * 264 + tid * 8 + 256] = v[j];
    }
  }
  __syncthreads();   // drains vmcnt (global_load_lds) + lgkmcnt

  // per-lane constants
  int vbase[4];
#pragma unroll
  for (int ni = 0; ni < 4; ++ni) {
    int d = ni * 16 + l15;
    vbase[ni] = d * 264 + ((ni * 2 + (l15 >> 3)) & 7) * 8;
  }
  float v256[4];
#pragma unroll
  for (int ni = 0; ni < 4; ++ni) v256[ni] = (float)Vt[vbase[ni] + 256];
  __bf16* Pw = Pbuf + wave * (16 * 40);
  const int sw = l15 & 7;                       // (row&7) for K frag reads
  const __bf16* kb = Ks + l15 * 64;

  for (int rt = wave; rt < 17; rt += 4) {
    const unsigned qo = rowoff(rt * 16 + l15);
    bf16x8 qf0 = *(const bf16x8*)((const char*)qkv + qo + qoffB + quad * 16);
    bf16x8 qf1 = *(const bf16x8*)((const char*)qkv + qo + qoffB + 64 + quad * 16);

    floatx4 zero = {0.f, 0.f, 0.f, 0.f};
    floatx4 s[17];
#pragma unroll
    for (int i = 0; i < 17; ++i) s[i] = zero;
#pragma unroll
    for (int k2 = 0; k2 < 17; ++k2) {
      const __bf16* kr = kb + k2 * 1024;
      bf16x8 kf0 = *(const bf16x8*)(kr + ((quad ^ sw) << 3));
      bf16x8 kf1 = *(const bf16x8*)(kr + (((quad + 4) ^ sw) << 3));
      s[k2] = mfma_16x16x32(qf0, kf0, s[k2]);
      s[k2] = mfma_16x16x32(qf1, kf1, s[k2]);
    }

    // ---- softmax (scale folded into exp2; mask only tile 16) ----
    float mx[4] = {-3.0e38f, -3.0e38f, -3.0e38f, -3.0e38f};
#pragma unroll
    for (int k2 = 0; k2 < 16; ++k2)
#pragma unroll
      for (int r = 0; r < 4; ++r) mx[r] = fmaxf(mx[r], s[k2][r]);
#pragma unroll
    for (int r = 0; r < 4; ++r) {
      float v = (l15 == 0) ? s[16][r] : -3.0e38f;
      s[16][r] = v;
      mx[r] = fmaxf(mx[r], v);
    }
#pragma unroll
    for (int off = 1; off < 16; off <<= 1)
#pragma unroll
      for (int r = 0; r < 4; ++r) mx[r] = fmaxf(mx[r], __shfl_xor(mx[r], off, 16));
    const float c1 = 0.125f * 1.44269504f;  // scale * log2(e)
    float mb[4], sum[4] = {0.f, 0.f, 0.f, 0.f};
#pragma unroll
    for (int r = 0; r < 4; ++r) mb[r] = mx[r] * c1;
#pragma unroll
    for (int k2 = 0; k2 < 17; ++k2)
#pragma unroll
      for (int r = 0; r < 4; ++r) {
        float e = __builtin_amdgcn_exp2f(fmaf(s[k2][r], c1, -mb[r]));
        s[k2][r] = e;
        sum[r] += e;
      }
#pragma unroll
    for (int off = 1; off < 16; off <<= 1)
#pragma unroll
      for (int r = 0; r < 4; ++r) sum[r] += __shfl_xor(sum[r], off, 16);
    float rl[4];
#pragma unroll
    for (int r = 0; r < 4; ++r) rl[r] = 1.0f / sum[r];

    // ---- PV: keys 0..255 via MFMA (unnormalized P), key 256 scalar ----
    floatx4 o[4];
#pragma unroll
    for (int i = 0; i < 4; ++i) o[i] = zero;
#pragma unroll
    for (int ks = 0; ks < 8; ++ks) {
#pragma unroll
      for (int half = 0; half < 2; ++half) {
        int kt2 = ks * 2 + half;
#pragma unroll
        for (int r = 0; r < 4; ++r)
          Pw[(quad * 4 + r) * 40 + half * 16 + l15] = f2bf(s[kt2][r]);
      }
      asm volatile("s_waitcnt lgkmcnt(0)" ::: "memory");
      bf16x8 pf = *(const bf16x8*)(Pw + l15 * 40 + quad * 8);
#pragma unroll
      for (int ni = 0; ni < 4; ++ni) {
        bf16x8 vf = *(const bf16x8*)(Vt + vbase[ni] + ks * 32 + quad * 8);
        o[ni] = mfma_16x16x32(pf, vf, o[ni]);
      }
    }
    float p256[4];
#pragma unroll
    for (int r = 0; r < 4; ++r) p256[r] = __shfl(s[16][r], lane & 48, 64);
#pragma unroll
    for (int ni = 0; ni < 4; ++ni)
#pragma unroll
      for (int r = 0; r < 4; ++r)
        o[ni][r] = (o[ni][r] + p256[r] * v256[ni]) * rl[r];

    // ---- store ----
#pragma unroll
    for (int r = 0; r < 4; ++r) {
      int q = rt * 16 + quad * 4 + r;
      if (q > 256) continue;
      if (q == 0) {
#pragma unroll
        for (int ni = 0; ni < 4; ++ni)
          outcls[(long)chunk * 512 + h * 64 + ni * 16 + l15] = o[ni][r];
      } else {
        long orow = (long)order[cs + q - 1];
#pragma unroll
        for (int ni = 0; ni < 4; ++ni)
          outO[orow * 512 + h * 64 + ni * 16 + l15] = f2bf(o[ni][r]);
      }
    }
  }
}

// cls_feat[b][c] = mean over batch-b chunks of outcls[chunk][c]
__global__ void cls_feat_kernel(const float* __restrict__ outcls,
                                const int* __restrict__ offset,
                                float* __restrict__ dst, int B, int C) {
  int i = blockIdx.x * blockDim.x + threadIdx.x;
  if (i >= B * C) return;
  int b = i / C, c = i - b * C;
  int st = (b == 0) ? 0 : offset[b - 1];
  int en = offset[b];
  int c0 = st >> 8, c1 = en >> 8;
  float s = 0.f;
  for (int ch = c0; ch < c1; ++ch) s += outcls[(long)ch * C + c];
  dst[i] = s / (float)(c1 - c0);
}

// ---------------------------------------------------------------------------
extern "C" void kernel_launch(void* const* d_in, const int* in_sizes, int n_in,
                              void* d_out, int out_size, void* d_ws, size_t ws_size,
                              hipStream_t stream) {
  const float* feat       = (const float*)d_in[0];
  const float* cls_tokens = (const float*)d_in[1];
  const float* Wqkv       = (const float*)d_in[2];
  const float* bqkv       = (const float*)d_in[3];
  const float* Wproj      = (const float*)d_in[4];
  const float* bproj      = (const float*)d_in[5];
  const int*   order      = (const int*)d_in[6];
  const int*   offset     = (const int*)d_in[8];
  const int B = in_sizes[8];  // 4

  char* ws = (char*)d_ws;
  __bf16* qkv    = (__bf16*)(ws);                   // 65536*1536*2 = 201326592
  __bf16* featb  = (__bf16*)(ws + 201326592);       // 65536*512*2  =  67108864
  __bf16* outO   = featb;                           // reuse after gemm1
  __bf16* wqkvT  = (__bf16*)(ws + 268435456);       // 1536*512*2
  __bf16* wprojT = (__bf16*)(ws + 270008320);       // 512*512*2
  __bf16* clsqkv = (__bf16*)(ws + 270532608);       // 4*1536*2
  float*  outcls = (float*)(ws + 270544896);        // 256*512*4

  float* feat_out = (float*)d_out;
  float* cls_out  = feat_out + (long)65536 * 512;

  cast_gather_feat<<<16384, 256, 0, stream>>>(feat, order, featb);
  transpose_cast<<<dim3(48, 16), 256, 0, stream>>>(Wqkv, wqkvT, 512, 1536);
  transpose_cast<<<dim3(16, 16), 256, 0, stream>>>(Wproj, wprojT, 512, 512);
  cls_qkv_kernel<<<96, 256, 0, stream>>>(cls_tokens, Wqkv, bqkv, clsqkv, 1536);

  // grid: x = col-blocks (fast) so A row-tile is shared by consecutive blocks
  gemm_bt<0><<<dim3(12, 512), 256, 0, stream>>>(featb, wqkvT, bqkv, (void*)qkv, 1536, 512);

  attn_kernel<<<2048, 256, 0, stream>>>(qkv, clsqkv, order, offset, outO, outcls, B);

  gemm_bt<1><<<dim3(4, 512), 256, 0, stream>>>(outO, wprojT, bproj, (void*)feat_out, 512, 512);

  cls_feat_kernel<<<8, 256, 0, stream>>>(outcls, offset, cls_out, B, 512);
}